// Round 11
// baseline (161.629 us; speedup 1.0000x reference)
//
#include <hip/hip_runtime.h>

// Problem constants
#define BB 8
#define NN 4096
#define CC 128
#define RR 16
#define EE 65536
#define NNODES 32768
#define NEDGES 524288
#define BCAP  48                 // per-dst bucket capacity (Poisson16: P(ovf)~2e-6 over all nodes)
#define SCE   15                 // entries per srt row; slot 0 holds the count
#define NT    32                 // nodes per agg block (8 threads/node) — R4-verified best
#define ALP   136                // A-tile LDS row stride (shorts): 272B, 16B-aligned

typedef unsigned short ushort_t;
typedef short bf16x8 __attribute__((ext_vector_type(8)));
typedef float f32x4 __attribute__((ext_vector_type(4)));

__device__ __forceinline__ unsigned short f2b(float f) {
    unsigned u = __builtin_bit_cast(unsigned, f);
    unsigned r = (u + 0x7fffu + ((u >> 16) & 1u)) >> 16;   // RNE
    return (unsigned short)r;
}
__device__ __forceinline__ float b2f(unsigned short s) {
    return __builtin_bit_cast(float, (unsigned)s << 16);
}
__device__ __forceinline__ float ldf(const void* p, int j, int isbf) {
    return isbf ? b2f(((const ushort_t*)p)[j]) : ((const float*)p)[j];
}
__device__ __forceinline__ int ldi(const int* p, int j, int is64) {
    return p[j << is64];
}
// v_cvt_pk_bf16_f32: D = {hi=bf16(s1), lo=bf16(s0)}, RNE
__device__ __forceinline__ unsigned cvtpk(float lo, float hi) {
    unsigned r;
    asm("v_cvt_pk_bf16_f32 %0, %1, %2" : "=v"(r) : "v"(lo), "v"(hi));
    return r;
}

// sum 8 bf16 (one uint4) into s[sb..sb+7] as fp32
#define GSUM8(u, sb) do { \
    s[sb+0] += __builtin_bit_cast(float, (u).x << 16); \
    s[sb+1] += __builtin_bit_cast(float, (u).x & 0xffff0000u); \
    s[sb+2] += __builtin_bit_cast(float, (u).y << 16); \
    s[sb+3] += __builtin_bit_cast(float, (u).y & 0xffff0000u); \
    s[sb+4] += __builtin_bit_cast(float, (u).z << 16); \
    s[sb+5] += __builtin_bit_cast(float, (u).z & 0xffff0000u); \
    s[sb+6] += __builtin_bit_cast(float, (u).w << 16); \
    s[sb+7] += __builtin_bit_cast(float, (u).w & 0xffff0000u); \
} while (0)

// ---------- prep_k (R4-verified: 1092 blocks) ----------
// [0,512): edge bucketing, 4 edges/thread, batch = bx&7 (XCD-affine with agg).
//          dcnt line-padded: one counter per 64B line.
// [512,1024): cast x -> Xb bf16, 4 x uint4/thread, batch-affine.
// [1024,1092): WT3 fragment-major swizzle: each MFMA B-frag = ONE contiguous 1KB wave-load.
__global__ __launch_bounds__(256) void prep_k(const void* __restrict__ x,
                                              const void* __restrict__ relw,
                                              const void* __restrict__ rootw,
                                              const int* __restrict__ ei,
                                              const int* __restrict__ et,
                                              ushort_t* __restrict__ Xb,
                                              ushort_t* __restrict__ WT3,
                                              int* __restrict__ dcnt,
                                              int* __restrict__ bucket,
                                              int isbf, int w64i, int w64t) {
    int bx = blockIdx.x, t = threadIdx.x;
    if (bx < 512) {                        // ---- edge path ----
        int b = bx & 7;                    // batch -> XCD affinity
        #pragma unroll
        for (int i = 0; i < 4; ++i) {
            int e = (bx >> 3) * 1024 + i * 256 + t;     // < EE
            int src = ldi(ei, (b * 2) * EE + e, w64i);
            int dst = ldi(ei, (b * 2 + 1) * EE + e, w64i);
            int r = ldi(et, (b << 16) + e, w64t);
            int gd = (b << 12) + dst;
            int pos = atomicAdd(&dcnt[gd << 4], 1);
            if (pos < BCAP)
                bucket[gd * BCAP + pos] = (((b << 12) + src) << 4) | r;
        }
    } else if (bx < 1024) {                // ---- cast_x, batch-affine ----
        int bx2 = bx - 512;
        int base = (bx2 & 7) * 65536 + (bx2 >> 3) * 256 + t;
        #pragma unroll
        for (int i = 0; i < 4; ++i) {
            int tid = base + i * 16384;                 // < 524288 uint4
            if (isbf) {
                ((uint4*)Xb)[tid] = ((const uint4*)x)[tid];
            } else {
                const float4* xf = (const float4*)x;
                float4 a = xf[2 * tid], b = xf[2 * tid + 1];
                ushort4 o0, o1;
                o0.x = f2b(a.x); o0.y = f2b(a.y); o0.z = f2b(a.z); o0.w = f2b(a.w);
                o1.x = f2b(b.x); o1.y = f2b(b.y); o1.z = f2b(b.z); o1.w = f2b(b.w);
                ((ushort4*)Xb)[2 * tid] = o0; ((ushort4*)Xb)[2 * tid + 1] = o1;
            }
        }
    } else {                               // ---- WT3 fragment-major build ----
        __shared__ ushort_t Ls[128 * 40];  // [c][k] tile of 32 k-rows
        int mb = bx - 1024;                // 0..67
        int mat = mb >> 2, chunk = mb & 3; // pass, 32-k chunk (=ks)
        const void* src = (mat == 16) ? rootw : relw;
        int soff = (mat == 16) ? 0 : mat * 16384;
        int k0 = chunk * 32;
        #pragma unroll
        for (int i = 0; i < 16; ++i) {     // coalesced read: c fast
            int idx = t + i * 256;         // < 4096
            int k = idx >> 7, c = idx & 127;
            Ls[c * 40 + k] = f2b(ldf(src, soff + (k0 + k) * 128 + c, isbf));
        }
        __syncthreads();
        #pragma unroll
        for (int i = 0; i < 2; ++i) {      // frag-major write: contiguous 1KB per frag
            int idx = t + i * 256;         // < 512 = 8 cg x 64 lanes
            int cg = idx >> 6, lane = idx & 63;
            int lrow = lane & 15, lq = lane >> 4;
            uint4 v = *(const uint4*)(&Ls[(cg * 16 + lrow) * 40 + lq * 8]);
            *(uint4*)(WT3 + ((size_t)((mat * 4 + chunk) * 8 + cg)) * 512 + lane * 8) = v;
        }
    }
}

// ---- 2-deep gather staging macros (all names static — no runtime-indexed arrays) ----
// STAGE(k, set): read srt row k, issue <=4 edge-row load pairs; k==16 -> root row; k>16 -> nop
#define STAGE(k, a0_,b0_,a1_,b1_,a2_,b2_,a3_,b3_, cf_,ce_,row_) do { \
    if ((k) < 16) { \
        row_ = (nsub << 4) + (k); \
        uint4 q0 = *(const uint4*)(&srt[row_ << 4]); \
        cf_ = q0.x & 0xffffu; ce_ = cf_ > SCE ? SCE : cf_; \
        int e0 = q0.x >> 16, e1 = q0.y & 0xffffu, e2 = q0.y >> 16, e3 = q0.z & 0xffffu; \
        if (ce_ > 0) { const ushort_t* xr = Xb + (size_t)e0 * 128; a0_ = *(const uint4*)(xr + offA); b0_ = *(const uint4*)(xr + offB); } \
        if (ce_ > 1) { const ushort_t* xr = Xb + (size_t)e1 * 128; a1_ = *(const uint4*)(xr + offA); b1_ = *(const uint4*)(xr + offB); } \
        if (ce_ > 2) { const ushort_t* xr = Xb + (size_t)e2 * 128; a2_ = *(const uint4*)(xr + offA); b2_ = *(const uint4*)(xr + offB); } \
        if (ce_ > 3) { const ushort_t* xr = Xb + (size_t)e3 * 128; a3_ = *(const uint4*)(xr + offA); b3_ = *(const uint4*)(xr + offB); } \
    } else if ((k) == 16) { \
        const ushort_t* xr = Xb + (size_t)gn * 128; \
        a0_ = *(const uint4*)(xr + offA); b0_ = *(const uint4*)(xr + offB); \
        cf_ = -1; ce_ = 0; row_ = 0; \
    } \
} while (0)

// FINISH(AB, set): finish sums for the staged pass, pack, write A[AB] (AB is a literal)
#define FINISH(AB, a0_,b0_,a1_,b1_,a2_,b2_,a3_,b3_, cf_,ce_,row_) do { \
    if (cf_ < 0) {                          /* root pass: raw row copy */ \
        *(uint4*)(&A[AB][nsub * ALP + offA]) = a0_; \
        *(uint4*)(&A[AB][nsub * ALP + offB]) = b0_; \
    } else { \
        float s[16]; \
        _Pragma("unroll") for (int j = 0; j < 16; ++j) s[j] = 0.f; \
        if (ce_ > 0) { GSUM8(a0_, 0); GSUM8(b0_, 8); } \
        if (ce_ > 1) { GSUM8(a1_, 0); GSUM8(b1_, 8); } \
        if (ce_ > 2) { GSUM8(a2_, 0); GSUM8(b2_, 8); } \
        if (ce_ > 3) { GSUM8(a3_, 0); GSUM8(b3_, 8); } \
        if (ce_ > 4) {                      /* rare tail (P~0.4% per list) */ \
            for (int e4 = 4; e4 < ce_; ++e4) { \
                int gs = srt[(row_ << 4) + 1 + e4]; \
                const ushort_t* xr = Xb + (size_t)gs * 128; \
                uint4 ta = *(const uint4*)(xr + offA), tb = *(const uint4*)(xr + offB); \
                GSUM8(ta, 0); GSUM8(tb, 8); \
            } \
        } \
        float w = (cf_ > 0) ? 1.0f / (float)cf_ : 0.f; \
        uint4 va, vb; \
        va.x = cvtpk(s[0] * w, s[1] * w);   va.y = cvtpk(s[2] * w, s[3] * w); \
        va.z = cvtpk(s[4] * w, s[5] * w);   va.w = cvtpk(s[6] * w, s[7] * w); \
        vb.x = cvtpk(s[8] * w, s[9] * w);   vb.y = cvtpk(s[10] * w, s[11] * w); \
        vb.z = cvtpk(s[12] * w, s[13] * w); vb.w = cvtpk(s[14] * w, s[15] * w); \
        *(uint4*)(&A[AB][nsub * ALP + offA]) = va; \
        *(uint4*)(&A[AB][nsub * ALP + offB]) = vb; \
    } \
} while (0)

#define MFMACL(AB, p) do { \
    const ushort_t* bw = WT3 + (size_t)(p) * 16384 + (wave * 2) * 512 + lane * 8; \
    __builtin_amdgcn_s_setprio(1); \
    _Pragma("unroll") \
    for (int ks = 0; ks < 4; ++ks) { \
        int k0 = ks * 32 + lq * 8; \
        bf16x8 a0 = *(const bf16x8*)(&A[AB][lrow * ALP + k0]); \
        bf16x8 a1 = *(const bf16x8*)(&A[AB][(16 + lrow) * ALP + k0]); \
        bf16x8 b0 = *(const bf16x8*)(bw + ks * 4096); \
        bf16x8 b1 = *(const bf16x8*)(bw + ks * 4096 + 512); \
        acc[0][0] = __builtin_amdgcn_mfma_f32_16x16x32_bf16(a0, b0, acc[0][0], 0, 0, 0); \
        acc[0][1] = __builtin_amdgcn_mfma_f32_16x16x32_bf16(a0, b1, acc[0][1], 0, 0, 0); \
        acc[1][0] = __builtin_amdgcn_mfma_f32_16x16x32_bf16(a1, b0, acc[1][0], 0, 0, 0); \
        acc[1][1] = __builtin_amdgcn_mfma_f32_16x16x32_bf16(a1, b1, acc[1][1], 0, 0, 0); \
    } \
    __builtin_amdgcn_s_setprio(0); \
} while (0)

// ---------- agg_k: R4 structure + 2-deep gather pipeline ----------
// Block = 32 nodes of one batch (bx&7 -> XCD L2 affinity), 256 threads, 8/node.
// Loads for pass p+2 are issued before MFMA(p); finished after MFMA(p+1) —
// ~2 MFMA clusters + barrier of latency cover instead of 1 (R4). Two named
// register sets, manual 2-pass loop unroll -> all indexing static (no scratch).
__global__ __launch_bounds__(256, 4) void agg_k(const ushort_t* __restrict__ Xb,
                                                const ushort_t* __restrict__ WT3,
                                                const int* __restrict__ dcnt,
                                                const int* __restrict__ bucket,
                                                const void* __restrict__ bias,
                                                const void* __restrict__ linw,
                                                const void* __restrict__ linb,
                                                void* __restrict__ out,
                                                int isbf) {
    __shared__ int scnt[NT * 16];              // sort-phase counts (2KB)
    __shared__ ushort_t srt[NT * 16 * 16];     // [row][0]=count,[1..15]=srcs (16KB)
    __shared__ ushort_t A[2][NT * ALP];        // double-buffered A-tile (17.4KB)
    __shared__ float red[NT][5];
    int bx = blockIdx.x, t = threadIdx.x;
    int n0 = (bx & 7) * NN + (bx >> 3) * NT;

    scnt[t] = 0; scnt[256 + t] = 0;
    __syncthreads();

    int nsub = t >> 3, tsub = t & 7;           // node-in-tile, 8 threads/node
    int gn = n0 + nsub;
    int offA = tsub * 8, offB = 64 + tsub * 8; // two 8-col octets per thread
    int nc = dcnt[gn << 4]; if (nc > BCAP) nc = BCAP;
    const int* bk = bucket + gn * BCAP;
    for (int j = tsub; j < nc; j += 8) {
        int v = bk[j];
        int row = (nsub << 4) + (v & 15);
        int pos = atomicAdd(&scnt[row], 1);
        if (pos < SCE)
            srt[(row << 4) + 1 + pos] = (ushort_t)((unsigned)v >> 4);
    }
    __syncthreads();
    srt[t << 4] = (ushort_t)scnt[t];           // fold counts into srt slot 0
    srt[(t + 256) << 4] = (ushort_t)scnt[t + 256];
    __syncthreads();

    int wave = t >> 6, lane = t & 63, lrow = lane & 15, lq = lane >> 4;
    f32x4 acc[2][2] = {};

    // two staging register sets (static names)
    uint4 p0a0, p0b0, p0a1, p0b1, p0a2, p0b2, p0a3, p0b3; int cf0, ce0, row0;
    uint4 p1a0, p1b0, p1a1, p1b1, p1a2, p1b2, p1a3, p1b3; int cf1, ce1, row1;

    // prologue: build A[0] for relation 0 (serial, once)
    {
        int row = nsub << 4;
        uint4 q0 = *(const uint4*)(&srt[row << 4]);
        int cf = q0.x & 0xffffu; int ce = cf > SCE ? SCE : cf;
        float s[16];
        #pragma unroll
        for (int j = 0; j < 16; ++j) s[j] = 0.f;
        for (int e = 0; e < ce; ++e) {
            int gs = srt[(row << 4) + 1 + e];
            const ushort_t* xr = Xb + (size_t)gs * 128;
            uint4 ua = *(const uint4*)(xr + offA), ub = *(const uint4*)(xr + offB);
            GSUM8(ua, 0); GSUM8(ub, 8);
        }
        float w = (cf > 0) ? 1.0f / (float)cf : 0.f;
        uint4 va, vb;
        va.x = cvtpk(s[0] * w, s[1] * w);   va.y = cvtpk(s[2] * w, s[3] * w);
        va.z = cvtpk(s[4] * w, s[5] * w);   va.w = cvtpk(s[6] * w, s[7] * w);
        vb.x = cvtpk(s[8] * w, s[9] * w);   vb.y = cvtpk(s[10] * w, s[11] * w);
        vb.z = cvtpk(s[12] * w, s[13] * w); vb.w = cvtpk(s[14] * w, s[15] * w);
        *(uint4*)(&A[0][nsub * ALP + offA]) = va;
        *(uint4*)(&A[0][nsub * ALP + offB]) = vb;
    }
    // stage pass 1 into set0 (loads fly across the sync + MFMA(0))
    STAGE(1, p0a0,p0b0,p0a1,p0b1,p0a2,p0b2,p0a3,p0b3, cf0,ce0,row0);
    __syncthreads();

    // main loop: 2 passes per iteration, 2-deep staging
    for (int pb = 0; pb < 8; ++pb) {
        int p0 = 2 * pb, p1 = p0 + 1;
        STAGE(p0 + 2, p1a0,p1b0,p1a1,p1b1,p1a2,p1b2,p1a3,p1b3, cf1,ce1,row1);
        MFMACL(0, p0);
        FINISH(1, p0a0,p0b0,p0a1,p0b1,p0a2,p0b2,p0a3,p0b3, cf0,ce0,row0);   // pass p0+1
        __syncthreads();
        STAGE(p1 + 2, p0a0,p0b0,p0a1,p0b1,p0a2,p0b2,p0a3,p0b3, cf0,ce0,row0);
        MFMACL(1, p1);
        FINISH(0, p1a0,p1b0,p1a1,p1b1,p1a2,p1b2,p1a3,p1b3, cf1,ce1,row1);   // pass p0+2
        __syncthreads();
    }
    MFMACL(0, 16);                             // tail: root pass

    // Epilogue: out[n][c] = relu(acc + bias[c]) * linw[c], reduce over c
    int wn = wave << 5;
    int c0 = wn + lrow, c1 = wn + 16 + lrow;
    float bi0 = ldf(bias, c0, isbf), bi1 = ldf(bias, c1, isbf);
    float lw0 = ldf(linw, c0, isbf), lw1 = ldf(linw, c1, isbf);
    #pragma unroll
    for (int mi = 0; mi < 2; ++mi)
        #pragma unroll
        for (int rg = 0; rg < 4; ++rg) {
            float p = fmaxf(acc[mi][0][rg] + bi0, 0.f) * lw0
                    + fmaxf(acc[mi][1][rg] + bi1, 0.f) * lw1;
            p += __shfl_xor(p, 1, 64);
            p += __shfl_xor(p, 2, 64);
            p += __shfl_xor(p, 4, 64);
            p += __shfl_xor(p, 8, 64);
            if (lrow == 0) red[mi * 16 + lq * 4 + rg][wave] = p;
        }
    __syncthreads();
    if (t < NT) {
        float res = red[t][0] + red[t][1] + red[t][2] + red[t][3] + ldf(linb, 0, isbf);
        if (isbf) ((ushort_t*)out)[n0 + t] = f2b(res);
        else      ((float*)out)[n0 + t] = res;
    }
}

extern "C" void kernel_launch(void* const* d_in, const int* in_sizes, int n_in,
                              void* d_out, int out_size, void* d_ws, size_t ws_size,
                              hipStream_t stream) {
    const void* x     = d_in[0];
    const int*  ei    = (const int*)d_in[1];
    const int*  et    = (const int*)d_in[2];
    const void* relw  = d_in[3];
    const void* rootw = d_in[4];
    const void* bias  = d_in[5];
    const void* linw  = d_in[6];
    const void* linb  = d_in[7];

    // Host-side dtype dispatch from input byte sizes
    int isbf = (in_sizes[0] == BB * NN * CC * 2);        // bf16 features
    int w64i = (in_sizes[1] == BB * 2 * EE * 8);         // int64 edge_index
    int w64t = (in_sizes[2] == BB * EE * 8);             // int64 edge_type

    const size_t WS_NEED = 17334272;
    if (ws_size < WS_NEED) return;

    char* ws = (char*)d_ws;
    ushort_t* Xb     = (ushort_t*)(ws);                       //  8,388,608
    ushort_t* WT3    = (ushort_t*)(ws + 8388608);             //    557,056
    int*      dcnt   = (int*)(ws + 8945664);                  //  2,097,152 (line-padded)
    int*      bucket = (int*)(ws + 11042816);                 //  6,291,456 (32768*48*4)

    hipMemsetAsync(dcnt, 0, 2097152, stream);
    prep_k<<<1092, 256, 0, stream>>>(x, relw, rootw, ei, et, Xb, WT3, dcnt, bucket,
                                     isbf, w64i, w64t);
    agg_k<<<1024, 256, 0, stream>>>(Xb, WT3, dcnt, bucket, bias, linw, linb, d_out, isbf);
}

// Round 12
// 146.100 us; speedup vs baseline: 1.1063x; 1.1063x over previous
//
#include <hip/hip_runtime.h>

// Problem constants
#define BB 8
#define NN 4096
#define CC 128
#define RR 16
#define EE 65536
#define NNODES 32768
#define NEDGES 524288
#define BCAP  48                 // per-dst bucket capacity (Poisson16: P(ovf)~2e-6 over all nodes)
#define SCAP  16                 // per-(node,rel) list capacity (Poisson1: P(ovf)~1e-14)
#define NT    32                 // nodes per agg block (8 threads/node) — R4-verified best
#define ALP   136                // A-tile LDS row stride (shorts): 272B, 16B-aligned

typedef unsigned short ushort_t;
typedef short bf16x8 __attribute__((ext_vector_type(8)));
typedef float f32x4 __attribute__((ext_vector_type(4)));
typedef float f32x2 __attribute__((ext_vector_type(2)));

__device__ __forceinline__ unsigned short f2b(float f) {
    unsigned u = __builtin_bit_cast(unsigned, f);
    unsigned r = (u + 0x7fffu + ((u >> 16) & 1u)) >> 16;   // RNE
    return (unsigned short)r;
}
__device__ __forceinline__ float b2f(unsigned short s) {
    return __builtin_bit_cast(float, (unsigned)s << 16);
}
__device__ __forceinline__ float ldf(const void* p, int j, int isbf) {
    return isbf ? b2f(((const ushort_t*)p)[j]) : ((const float*)p)[j];
}
__device__ __forceinline__ int ldi(const int* p, int j, int is64) {
    return p[j << is64];
}
// v_cvt_pk_bf16_f32: D = {hi=bf16(s1), lo=bf16(s0)}, RNE
__device__ __forceinline__ unsigned cvtpk(float lo, float hi) {
    unsigned r;
    asm("v_cvt_pk_bf16_f32 %0, %1, %2" : "=v"(r) : "v"(lo), "v"(hi));
    return r;
}
__device__ __forceinline__ float bcf(unsigned u) { return __builtin_bit_cast(float, u); }

// sum 8 bf16 (one uint4) into 4 packed f32-pair accumulators (v_pk_add_f32):
// half the VALU issues of the scalar GSUM8.
#define GSUM8PA(u) do { \
    s2[0] += (f32x2){bcf((u).x << 16), bcf((u).x & 0xffff0000u)}; \
    s2[1] += (f32x2){bcf((u).y << 16), bcf((u).y & 0xffff0000u)}; \
    s2[2] += (f32x2){bcf((u).z << 16), bcf((u).z & 0xffff0000u)}; \
    s2[3] += (f32x2){bcf((u).w << 16), bcf((u).w & 0xffff0000u)}; \
} while (0)
#define GSUM8PB(u) do { \
    s2[4] += (f32x2){bcf((u).x << 16), bcf((u).x & 0xffff0000u)}; \
    s2[5] += (f32x2){bcf((u).y << 16), bcf((u).y & 0xffff0000u)}; \
    s2[6] += (f32x2){bcf((u).z << 16), bcf((u).z & 0xffff0000u)}; \
    s2[7] += (f32x2){bcf((u).w << 16), bcf((u).w & 0xffff0000u)}; \
} while (0)

// ---------- prep_k (R10-verified) ----------
// [0,512): edge bucketing, 4 edges/thread, batch = bx&7 (XCD-affine with agg).
//          dcnt line-padded: one counter per 64B line.
// [512,1024): cast x -> Xb bf16, 4 x uint4/thread, batch-affine.
// [1024,1092): WT3 fragment-major swizzle: each MFMA B-frag = ONE contiguous 1KB wave-load.
__global__ __launch_bounds__(256) void prep_k(const void* __restrict__ x,
                                              const void* __restrict__ relw,
                                              const void* __restrict__ rootw,
                                              const int* __restrict__ ei,
                                              const int* __restrict__ et,
                                              ushort_t* __restrict__ Xb,
                                              ushort_t* __restrict__ WT3,
                                              int* __restrict__ dcnt,
                                              int* __restrict__ bucket,
                                              int isbf, int w64i, int w64t) {
    int bx = blockIdx.x, t = threadIdx.x;
    if (bx < 512) {                        // ---- edge path ----
        int b = bx & 7;                    // batch -> XCD affinity
        #pragma unroll
        for (int i = 0; i < 4; ++i) {
            int e = (bx >> 3) * 1024 + i * 256 + t;     // < EE
            int src = ldi(ei, (b * 2) * EE + e, w64i);
            int dst = ldi(ei, (b * 2 + 1) * EE + e, w64i);
            int r = ldi(et, (b << 16) + e, w64t);
            int gd = (b << 12) + dst;
            int pos = atomicAdd(&dcnt[gd << 4], 1);
            if (pos < BCAP)
                bucket[gd * BCAP + pos] = (((b << 12) + src) << 4) | r;
        }
    } else if (bx < 1024) {                // ---- cast_x, batch-affine ----
        int bx2 = bx - 512;
        int base = (bx2 & 7) * 65536 + (bx2 >> 3) * 256 + t;
        #pragma unroll
        for (int i = 0; i < 4; ++i) {
            int tid = base + i * 16384;                 // < 524288 uint4
            if (isbf) {
                ((uint4*)Xb)[tid] = ((const uint4*)x)[tid];
            } else {
                const float4* xf = (const float4*)x;
                float4 a = xf[2 * tid], b = xf[2 * tid + 1];
                ushort4 o0, o1;
                o0.x = f2b(a.x); o0.y = f2b(a.y); o0.z = f2b(a.z); o0.w = f2b(a.w);
                o1.x = f2b(b.x); o1.y = f2b(b.y); o1.z = f2b(b.z); o1.w = f2b(b.w);
                ((ushort4*)Xb)[2 * tid] = o0; ((ushort4*)Xb)[2 * tid + 1] = o1;
            }
        }
    } else {                               // ---- WT3 fragment-major build ----
        __shared__ ushort_t Ls[128 * 40];  // [c][k] tile of 32 k-rows
        int mb = bx - 1024;                // 0..67
        int mat = mb >> 2, chunk = mb & 3; // pass, 32-k chunk (=ks)
        const void* src = (mat == 16) ? rootw : relw;
        int soff = (mat == 16) ? 0 : mat * 16384;
        int k0 = chunk * 32;
        #pragma unroll
        for (int i = 0; i < 16; ++i) {     // coalesced read: c fast
            int idx = t + i * 256;         // < 4096
            int k = idx >> 7, c = idx & 127;
            Ls[c * 40 + k] = f2b(ldf(src, soff + (k0 + k) * 128 + c, isbf));
        }
        __syncthreads();
        #pragma unroll
        for (int i = 0; i < 2; ++i) {      // frag-major write: contiguous 1KB per frag
            int idx = t + i * 256;         // < 512 = 8 cg x 64 lanes
            int cg = idx >> 6, lane = idx & 63;
            int lrow = lane & 15, lq = lane >> 4;
            uint4 v = *(const uint4*)(&Ls[(cg * 16 + lrow) * 40 + lq * 8]);
            *(uint4*)(WT3 + ((size_t)((mat * 4 + chunk) * 8 + cg)) * 512 + lane * 8) = v;
        }
    }
}

// ---------- agg_k: R4-verified 49us structure + packed-f32 gather sums ----------
// Block = 32 nodes of one batch (bx&7 -> XCD L2 affinity), 256 threads, 8/node.
// Sort once into per-(node,rel) lists; then 17 passes: stage next-pass gather
// (counts from scnt LDS, list head via one ds_read_b128, <=4 edge-row loads in
// flight across the MFMA cluster), MFMA on A[p&1] with contiguous 1KB B-frags
// from WT3, finish pk-f32 sums + cvt_pk pack into A[(p+1)&1], 1 barrier/pass.
__global__ __launch_bounds__(256, 4) void agg_k(const ushort_t* __restrict__ Xb,
                                                const ushort_t* __restrict__ WT3,
                                                const int* __restrict__ dcnt,
                                                const int* __restrict__ bucket,
                                                const void* __restrict__ bias,
                                                const void* __restrict__ linw,
                                                const void* __restrict__ linb,
                                                void* __restrict__ out,
                                                int isbf) {
    __shared__ int scnt[NT * 16];              // per-(node,rel) counts
    __shared__ ushort_t srt[NT * 16 * SCAP];   // sorted src lists (16KB)
    __shared__ ushort_t A[2][NT * ALP];        // double-buffered A-tile (17.4KB)
    __shared__ float red[NT][5];
    int bx = blockIdx.x, t = threadIdx.x;
    int n0 = (bx & 7) * NN + (bx >> 3) * NT;

    scnt[t] = 0; scnt[256 + t] = 0;
    __syncthreads();

    int nsub = t >> 3, tsub = t & 7;           // node-in-tile, 8 threads/node
    int gn = n0 + nsub;
    int offA = tsub * 8, offB = 64 + tsub * 8; // two contiguous 8-col octets
    int nc = dcnt[gn << 4]; if (nc > BCAP) nc = BCAP;
    const int* bk = bucket + gn * BCAP;
    for (int j = tsub; j < nc; j += 8) {
        int v = bk[j];
        int pos = atomicAdd(&scnt[(nsub << 4) + (v & 15)], 1);
        if (pos < SCAP)
            srt[(((nsub << 4) + (v & 15)) << 4) + pos] = (ushort_t)((unsigned)v >> 4);
    }
    __syncthreads();

    int wave = t >> 6, lane = t & 63, lrow = lane & 15, lq = lane >> 4;
    f32x4 acc[2][2] = {};

    // prologue: build A[0] for relation 0 (serial, once)
    {
        int cf = scnt[nsub << 4];
        int ce = cf > SCAP ? SCAP : cf;
        const ushort_t* lst = &srt[nsub << 8];
        f32x2 s2[8] = {};
        for (int e = 0; e < ce; ++e) {
            const ushort_t* xr = Xb + (size_t)lst[e] * 128;
            uint4 ua = *(const uint4*)(xr + offA), ub = *(const uint4*)(xr + offB);
            GSUM8PA(ua); GSUM8PB(ub);
        }
        f32x2 w2 = {0.f, 0.f};
        if (cf > 0) { float w = 1.0f / (float)cf; w2 = (f32x2){w, w}; }
        #pragma unroll
        for (int j = 0; j < 8; ++j) s2[j] *= w2;
        uint4 va, vb;
        va.x = cvtpk(s2[0].x, s2[0].y); va.y = cvtpk(s2[1].x, s2[1].y);
        va.z = cvtpk(s2[2].x, s2[2].y); va.w = cvtpk(s2[3].x, s2[3].y);
        vb.x = cvtpk(s2[4].x, s2[4].y); vb.y = cvtpk(s2[5].x, s2[5].y);
        vb.z = cvtpk(s2[6].x, s2[6].y); vb.w = cvtpk(s2[7].x, s2[7].y);
        *(uint4*)(&A[0][nsub * ALP + offA]) = va;
        *(uint4*)(&A[0][nsub * ALP + offB]) = vb;
    }
    __syncthreads();

    for (int p = 0; p < 17; ++p) {
        int np = p + 1;
        // ---- stage pass np: list head via 1 ds_read_b128, <=4 edge-rows in flight ----
        uint4 r0a, r0b, r1a, r1b, r2a, r2b, r3a, r3b;
        int cf = 0, ce = 0;
        if (np < 16) {
            cf = scnt[(nsub << 4) + np];
            ce = cf > SCAP ? SCAP : cf;
            uint4 q0 = *(const uint4*)(&srt[((nsub << 4) + np) << 4]);
            int e0 = q0.x & 0xffffu, e1 = q0.x >> 16;
            int e2i = q0.y & 0xffffu, e3 = q0.y >> 16;
            if (ce > 0) { const ushort_t* xr = Xb + (size_t)e0 * 128;  r0a = *(const uint4*)(xr + offA); r0b = *(const uint4*)(xr + offB); }
            if (ce > 1) { const ushort_t* xr = Xb + (size_t)e1 * 128;  r1a = *(const uint4*)(xr + offA); r1b = *(const uint4*)(xr + offB); }
            if (ce > 2) { const ushort_t* xr = Xb + (size_t)e2i * 128; r2a = *(const uint4*)(xr + offA); r2b = *(const uint4*)(xr + offB); }
            if (ce > 3) { const ushort_t* xr = Xb + (size_t)e3 * 128;  r3a = *(const uint4*)(xr + offA); r3b = *(const uint4*)(xr + offB); }
        } else if (np == 16) {             // root pass: plain row copy
            const ushort_t* xr = Xb + (size_t)gn * 128;
            r0a = *(const uint4*)(xr + offA); r0b = *(const uint4*)(xr + offB);
        }
        // ---- MFMA on A[p&1]; B-frags = contiguous 1KB loads from WT3 ----
        const ushort_t* Ap = A[p & 1];
        const ushort_t* bw = WT3 + (size_t)p * 16384 + (wave * 2) * 512 + lane * 8;
        __builtin_amdgcn_s_setprio(1);
        #pragma unroll
        for (int ks = 0; ks < 4; ++ks) {
            int k0 = ks * 32 + lq * 8;
            bf16x8 a0 = *(const bf16x8*)(&Ap[lrow * ALP + k0]);
            bf16x8 a1 = *(const bf16x8*)(&Ap[(16 + lrow) * ALP + k0]);
            bf16x8 b0 = *(const bf16x8*)(bw + ks * 4096);
            bf16x8 b1 = *(const bf16x8*)(bw + ks * 4096 + 512);
            acc[0][0] = __builtin_amdgcn_mfma_f32_16x16x32_bf16(a0, b0, acc[0][0], 0, 0, 0);
            acc[0][1] = __builtin_amdgcn_mfma_f32_16x16x32_bf16(a0, b1, acc[0][1], 0, 0, 0);
            acc[1][0] = __builtin_amdgcn_mfma_f32_16x16x32_bf16(a1, b0, acc[1][0], 0, 0, 0);
            acc[1][1] = __builtin_amdgcn_mfma_f32_16x16x32_bf16(a1, b1, acc[1][1], 0, 0, 0);
        }
        __builtin_amdgcn_s_setprio(0);
        // ---- finish pk-sums, pack A[np&1] ----
        if (np < 16) {
            f32x2 s2[8] = {};
            if (ce > 0) { GSUM8PA(r0a); GSUM8PB(r0b); }
            if (ce > 1) { GSUM8PA(r1a); GSUM8PB(r1b); }
            if (ce > 2) { GSUM8PA(r2a); GSUM8PB(r2b); }
            if (ce > 3) { GSUM8PA(r3a); GSUM8PB(r3b); }
            if (ce > 4) {                  // rare tail (P~0.4% per list)
                const ushort_t* lst = &srt[((nsub << 4) + np) << 4];
                for (int e4 = 4; e4 < ce; ++e4) {
                    const ushort_t* xr = Xb + (size_t)lst[e4] * 128;
                    uint4 ta = *(const uint4*)(xr + offA), tb = *(const uint4*)(xr + offB);
                    GSUM8PA(ta); GSUM8PB(tb);
                }
            }
            f32x2 w2 = {0.f, 0.f};
            if (cf > 0) { float w = 1.0f / (float)cf; w2 = (f32x2){w, w}; }
            #pragma unroll
            for (int j = 0; j < 8; ++j) s2[j] *= w2;
            uint4 va, vb;
            va.x = cvtpk(s2[0].x, s2[0].y); va.y = cvtpk(s2[1].x, s2[1].y);
            va.z = cvtpk(s2[2].x, s2[2].y); va.w = cvtpk(s2[3].x, s2[3].y);
            vb.x = cvtpk(s2[4].x, s2[4].y); vb.y = cvtpk(s2[5].x, s2[5].y);
            vb.z = cvtpk(s2[6].x, s2[6].y); vb.w = cvtpk(s2[7].x, s2[7].y);
            *(uint4*)(&A[np & 1][nsub * ALP + offA]) = va;
            *(uint4*)(&A[np & 1][nsub * ALP + offB]) = vb;
        } else if (np == 16) {
            *(uint4*)(&A[np & 1][nsub * ALP + offA]) = r0a;
            *(uint4*)(&A[np & 1][nsub * ALP + offB]) = r0b;
        }
        if (p < 16) __syncthreads();
    }

    // Epilogue: out[n][c] = relu(acc + bias[c]) * linw[c], reduce over c
    int wn = wave << 5;
    int c0 = wn + lrow, c1 = wn + 16 + lrow;
    float bi0 = ldf(bias, c0, isbf), bi1 = ldf(bias, c1, isbf);
    float lw0 = ldf(linw, c0, isbf), lw1 = ldf(linw, c1, isbf);
    #pragma unroll
    for (int mi = 0; mi < 2; ++mi)
        #pragma unroll
        for (int rg = 0; rg < 4; ++rg) {
            float p = fmaxf(acc[mi][0][rg] + bi0, 0.f) * lw0
                    + fmaxf(acc[mi][1][rg] + bi1, 0.f) * lw1;
            p += __shfl_xor(p, 1, 64);
            p += __shfl_xor(p, 2, 64);
            p += __shfl_xor(p, 4, 64);
            p += __shfl_xor(p, 8, 64);
            if (lrow == 0) red[mi * 16 + lq * 4 + rg][wave] = p;
        }
    __syncthreads();
    if (t < NT) {
        float res = red[t][0] + red[t][1] + red[t][2] + red[t][3] + ldf(linb, 0, isbf);
        if (isbf) ((ushort_t*)out)[n0 + t] = f2b(res);
        else      ((float*)out)[n0 + t] = res;
    }
}

extern "C" void kernel_launch(void* const* d_in, const int* in_sizes, int n_in,
                              void* d_out, int out_size, void* d_ws, size_t ws_size,
                              hipStream_t stream) {
    const void* x     = d_in[0];
    const int*  ei    = (const int*)d_in[1];
    const int*  et    = (const int*)d_in[2];
    const void* relw  = d_in[3];
    const void* rootw = d_in[4];
    const void* bias  = d_in[5];
    const void* linw  = d_in[6];
    const void* linb  = d_in[7];

    // Host-side dtype dispatch from input byte sizes
    int isbf = (in_sizes[0] == BB * NN * CC * 2);        // bf16 features
    int w64i = (in_sizes[1] == BB * 2 * EE * 8);         // int64 edge_index
    int w64t = (in_sizes[2] == BB * EE * 8);             // int64 edge_type

    const size_t WS_NEED = 17334272;
    if (ws_size < WS_NEED) return;

    char* ws = (char*)d_ws;
    ushort_t* Xb     = (ushort_t*)(ws);                       //  8,388,608
    ushort_t* WT3    = (ushort_t*)(ws + 8388608);             //    557,056
    int*      dcnt   = (int*)(ws + 8945664);                  //  2,097,152 (line-padded)
    int*      bucket = (int*)(ws + 11042816);                 //  6,291,456 (32768*48*4)

    hipMemsetAsync(dcnt, 0, 2097152, stream);
    prep_k<<<1092, 256, 0, stream>>>(x, relw, rootw, ei, et, Xb, WT3, dcnt, bucket,
                                     isbf, w64i, w64t);
    agg_k<<<1024, 256, 0, stream>>>(Xb, WT3, dcnt, bucket, bias, linw, linb, d_out, isbf);
}